// Round 3
// baseline (254.964 us; speedup 1.0000x reference)
//
#include <hip/hip_runtime.h>
#include <math.h>

// Problem constants (B=4, S=2048, H=1024, E=16, TOP_K=4)
constexpr int kTokens = 8192;   // B*S
constexpr int kH      = 1024;
constexpr int kE      = 16;
constexpr int kTopK   = 4;

// ---------------------------------------------------------------------------
// Stage 1: partial logits, one wave per (64-token group, h-chunk).
// Lane = token. h is WAVE-UNIFORM inside the FMA loop, so W[h][e] loads are
// scalar (SMEM path) — this removes the 2.1M-wave-instr vector weight traffic
// that pinned rounds 1-2 at ~100 us (L1 return-bandwidth bound, VALUBusy 8%).
// x is transposed through a per-wave LDS tile (coalesced global float4 loads;
// ds_read_b128 column reads at stride 68 floats touch all 32 banks uniformly).
// Single wave per block: no __syncthreads needed at all.
// NC = number of h-chunks (16 normally; 4 if ws_size is small).
// ---------------------------------------------------------------------------
template<int NC>
__global__ __launch_bounds__(64)
void router_gemv(const float* __restrict__ x,   const float* __restrict__ img,
                 const float* __restrict__ txt, const float* __restrict__ aud,
                 const float* __restrict__ Wg,  const float* __restrict__ Wi,
                 const float* __restrict__ Wt,  const float* __restrict__ Wa,
                 float* __restrict__ partials)
{
    constexpr int HC = kH / NC;    // h per chunk
    constexpr int NS = HC / 64;    // 64-h subtiles per chunk

    __shared__ float tile[64 * 68];   // [row=token][68]  17.4 KB

    const int lane = threadIdx.x;
    const int c    = blockIdx.x % NC;   // h-chunk
    const int tg   = blockIdx.x / NC;   // token group (128 groups of 64)
    const int tok0 = tg * 64;

    const float* Xs[4] = { x,  img, txt, aud };
    const float* Ws[4] = { Wg, Wi,  Wt,  Wa  };

    double dacc[kE];
#pragma unroll
    for (int e = 0; e < kE; ++e) dacc[e] = 0.0;

#pragma unroll
    for (int m = 0; m < 4; ++m) {
        const float* __restrict__ Xm = Xs[m];
        const float* __restrict__ Wm = Ws[m];

        for (int s = 0; s < NS; ++s) {
            const int h0 = c * HC + s * 64;

            // ---- stage x[64 tok][64 h] into LDS, fully coalesced ----
            {
                const int q = lane & 15;          // float4 column within row
                const int r0 = lane >> 4;         // 4 rows per instruction
#pragma unroll
                for (int it = 0; it < 16; ++it) {
                    const int r = it * 4 + r0;
                    const float4 v = *(const float4*)(Xm + (size_t)(tok0 + r) * kH + h0 + q * 4);
                    *(float4*)&tile[r * 68 + q * 4] = v;
                }
            }
            // single wave: compiler orders ds_write -> ds_read via lgkmcnt.

            // ---- compute: lane = token, h wave-uniform -> scalar weights ----
            float facc[kE];
#pragma unroll
            for (int e = 0; e < kE; ++e) facc[e] = 0.f;

#pragma unroll
            for (int hq = 0; hq < 16; ++hq) {
                const float4 xv = *(const float4*)&tile[lane * 68 + hq * 4];
#pragma unroll
                for (int j = 0; j < 4; ++j) {
                    const float xh = (j == 0) ? xv.x : (j == 1) ? xv.y : (j == 2) ? xv.z : xv.w;
                    const float* wr = Wm + (size_t)(h0 + hq * 4 + j) * kE;  // wave-uniform addr
                    const float4 w0 = *(const float4*)(wr + 0);
                    const float4 w1 = *(const float4*)(wr + 4);
                    const float4 w2 = *(const float4*)(wr + 8);
                    const float4 w3 = *(const float4*)(wr + 12);
                    facc[0]  += xh * w0.x;  facc[1]  += xh * w0.y;
                    facc[2]  += xh * w0.z;  facc[3]  += xh * w0.w;
                    facc[4]  += xh * w1.x;  facc[5]  += xh * w1.y;
                    facc[6]  += xh * w1.z;  facc[7]  += xh * w1.w;
                    facc[8]  += xh * w2.x;  facc[9]  += xh * w2.y;
                    facc[10] += xh * w2.z;  facc[11] += xh * w2.w;
                    facc[12] += xh * w3.x;  facc[13] += xh * w3.y;
                    facc[14] += xh * w3.z;  facc[15] += xh * w3.w;
                }
            }
            // fold 64-h fp32 span into fp64 (same numeric scheme as rounds 1-2)
#pragma unroll
            for (int e = 0; e < kE; ++e) dacc[e] += (double)facc[e];
        }
    }

    // ---- write fp32 partial [c][tok][e] ----
    const int tok = tok0 + lane;
    float* pp = partials + ((size_t)c * kTokens + tok) * kE;
#pragma unroll
    for (int q = 0; q < 4; ++q) {
        *(float4*)&pp[q * 4] = make_float4((float)dacc[q * 4 + 0], (float)dacc[q * 4 + 1],
                                           (float)dacc[q * 4 + 2], (float)dacc[q * 4 + 3]);
    }
}

// ---------------------------------------------------------------------------
// Stage 2: combine NC chunk-partials + biases (fp64), softmax, top-k, output
// writes, per-block expert sums. Block = 64 tokens x 256 threads.
// Accumulation phase: thread = (tok, e-quad) -> fully coalesced float4 loads.
// ---------------------------------------------------------------------------
template<int NC>
__global__ __launch_bounds__(256)
void router_topk(const float* __restrict__ partials,
                 const float* __restrict__ bg, const float* __restrict__ bi,
                 const float* __restrict__ bt, const float* __restrict__ ba,
                 float* __restrict__ out, float* __restrict__ blocksum)
{
    __shared__ double lgs[64][kE + 1];
    __shared__ float  pr[64][kE + 1];

    const int t    = threadIdx.x;
    const int tq   = t >> 2;      // token offset 0..63
    const int eq   = t & 3;       // e-quad
    const int tok0 = blockIdx.x * 64;

    double a0 = (double)bg[eq*4+0] + (double)bi[eq*4+0] + (double)bt[eq*4+0] + (double)ba[eq*4+0];
    double a1 = (double)bg[eq*4+1] + (double)bi[eq*4+1] + (double)bt[eq*4+1] + (double)ba[eq*4+1];
    double a2 = (double)bg[eq*4+2] + (double)bi[eq*4+2] + (double)bt[eq*4+2] + (double)ba[eq*4+2];
    double a3 = (double)bg[eq*4+3] + (double)bi[eq*4+3] + (double)bt[eq*4+3] + (double)ba[eq*4+3];

#pragma unroll
    for (int c = 0; c < NC; ++c) {
        const float4 v = *(const float4*)(partials + ((size_t)c * kTokens + tok0 + tq) * kE + eq * 4);
        a0 += (double)v.x;  a1 += (double)v.y;  a2 += (double)v.z;  a3 += (double)v.w;
    }
    lgs[tq][eq*4+0] = a0;  lgs[tq][eq*4+1] = a1;
    lgs[tq][eq*4+2] = a2;  lgs[tq][eq*4+3] = a3;
    __syncthreads();

    if (t < 64) {
        const int tok = tok0 + t;
        double lg[kE];
#pragma unroll
        for (int e = 0; e < kE; ++e) lg[e] = lgs[t][e];

        double mx = lg[0];
#pragma unroll
        for (int e = 1; e < kE; ++e) mx = fmax(mx, lg[e]);

        float p[kE];
        float sum = 0.f;
#pragma unroll
        for (int e = 0; e < kE; ++e) {
            p[e] = expf((float)(lg[e] - mx));
            sum += p[e];
        }
        const float inv = 1.f / sum;
#pragma unroll
        for (int e = 0; e < kE; ++e) { p[e] *= inv; pr[t][e] = p[e]; }

        // top-4, descending, ties -> smallest index (matches jax.lax.top_k)
        unsigned used = 0;
        float tp[kTopK];
        int   ti[kTopK];
        float s4 = 0.f;
#pragma unroll
        for (int k = 0; k < kTopK; ++k) {
            float best = -1.f;
            int   bidx = 0;
#pragma unroll
            for (int e = 0; e < kE; ++e) {
                if (!((used >> e) & 1u) && p[e] > best) { best = p[e]; bidx = e; }
            }
            used |= 1u << bidx;
            tp[k] = best;
            ti[k] = bidx;
            s4 += best;
        }
        const float rn = 1.f / s4;

        *(float4*)&out[(size_t)tok * kTopK] =
            make_float4((float)ti[0], (float)ti[1], (float)ti[2], (float)ti[3]);
        *(float4*)&out[(size_t)kTokens * kTopK + (size_t)tok * kTopK] =
            make_float4(tp[0] * rn, tp[1] * rn, tp[2] * rn, tp[3] * rn);
    }
    __syncthreads();

    if (t < kE) {
        float s = 0.f;
#pragma unroll
        for (int tk = 0; tk < 64; ++tk) s += pr[tk][t];
        blocksum[blockIdx.x * kE + t] = s;
    }
}

// ---------------------------------------------------------------------------
// Stage 3: 128 block-partials -> mean prob per expert -> aux loss scalar
// ---------------------------------------------------------------------------
__global__ __launch_bounds__(64)
void router_aux(const float* __restrict__ blocksum, float* __restrict__ out)
{
    __shared__ double ps[kE];
    const int t = threadIdx.x;
    if (t < kE) {
        double s = 0.0;
        for (int b = 0; b < 128; ++b) s += (double)blocksum[b * kE + t];
        ps[t] = s / (double)kTokens;
    }
    __syncthreads();
    if (t == 0) {
        double aux = 0.0;
#pragma unroll
        for (int e = 0; e < kE; ++e) aux += ps[e] * log(ps[e] * (double)kE + 1e-9);
        out[(size_t)kTokens * kTopK * 2] = (float)aux;  // element 65536
    }
}

extern "C" void kernel_launch(void* const* d_in, const int* in_sizes, int n_in,
                              void* d_out, int out_size, void* d_ws, size_t ws_size,
                              hipStream_t stream)
{
    const float* x   = (const float*)d_in[0];
    const float* img = (const float*)d_in[1];
    const float* txt = (const float*)d_in[2];
    const float* aud = (const float*)d_in[3];
    const float* Wg  = (const float*)d_in[4];
    const float* bg  = (const float*)d_in[5];
    const float* Wi  = (const float*)d_in[6];
    const float* bi  = (const float*)d_in[7];
    const float* Wt  = (const float*)d_in[8];
    const float* bt  = (const float*)d_in[9];
    const float* Wa  = (const float*)d_in[10];
    const float* ba  = (const float*)d_in[11];

    float* out = (float*)d_out;

    const size_t need16 = (size_t)16 * kTokens * kE * 4 + 128 * kE * 4;
    if (ws_size >= need16) {
        float* partials = (float*)d_ws;                                   // 8 MB
        float* blocksum = (float*)((char*)d_ws + (size_t)16 * kTokens * kE * 4);
        router_gemv<16><<<16 * 128, 64, 0, stream>>>(x, img, txt, aud, Wg, Wi, Wt, Wa, partials);
        router_topk<16><<<128, 256, 0, stream>>>(partials, bg, bi, bt, ba, out, blocksum);
        router_aux<<<1, 64, 0, stream>>>(blocksum, out);
    } else {
        float* partials = (float*)d_ws;                                   // 2 MB (round-2-proven)
        float* blocksum = (float*)((char*)d_ws + (size_t)4 * kTokens * kE * 4);
        router_gemv<4><<<4 * 128, 64, 0, stream>>>(x, img, txt, aud, Wg, Wi, Wt, Wa, partials);
        router_topk<4><<<128, 256, 0, stream>>>(partials, bg, bi, bt, ba, out, blocksum);
        router_aux<<<1, 64, 0, stream>>>(blocksum, out);
    }
}

// Round 4
// 183.350 us; speedup vs baseline: 1.3906x; 1.3906x over previous
//
#include <hip/hip_runtime.h>
#include <math.h>

// Problem constants (B=4, S=2048, H=1024, E=16, TOP_K=4)
constexpr int kTokens = 8192;   // B*S
constexpr int kH      = 1024;
constexpr int kE      = 16;
constexpr int kTopK   = 4;
constexpr int kNC     = 16;     // h-splits (64 h each)

// ---------------------------------------------------------------------------
// Stage 1: partial logits. Block = 256 threads = 4 waves, 64 tokens,
// one 64-h split, all 4 modalities. Grid = 128 token-groups x 16 h-splits
// = 2048 blocks, ~6 resident/CU (vs round 3's 1-wave/17KB blocks at 10% occ).
//
// Per pass (one modality x 32 h): 256 threads stage x[64 tok][32 h] into a
// double-buffered LDS tile (coalesced float4, prefetched before compute);
// wave w computes its 8-h sub-slice with lane = token. Weight addresses
// depend only on (blockIdx, readfirstlane(wave)) -> provably wave-uniform ->
// scalar s_load path (round 3 proved this: SGPR 112, FETCH unchanged).
// With ~24 waves/CU the s_load/ds_read latencies now overlap across waves.
//
// Numerics = round 3 (passed, 300x margin): fp32 accum over 16-h chunks,
// fp64 fold, block-level fp64 cross-wave reduce, fp32 partial per 64 h.
// ---------------------------------------------------------------------------
__global__ __launch_bounds__(256, 5)
void router_fmac(const float* __restrict__ x,   const float* __restrict__ img,
                 const float* __restrict__ txt, const float* __restrict__ aud,
                 const float* __restrict__ Wg,  const float* __restrict__ Wi,
                 const float* __restrict__ Wt,  const float* __restrict__ Wa,
                 float* __restrict__ partials)
{
    // 20 KB: two [64][36] tile buffers (stride 36 floats = 144 B: 16B-aligned,
    // bank-conflict-free per round-3 measurement); reused as red[4][64][20].
    __shared__ float smem[5120];

    const int t  = threadIdx.x;
    const int w  = __builtin_amdgcn_readfirstlane(t >> 6);  // wave id (SGPR)
    const int ln = t & 63;                                  // lane = token
    const int hs    = blockIdx.x & 15;   // h-split
    const int tg    = blockIdx.x >> 4;   // token group
    const int tok0  = tg * 64;
    const int hbase = hs * 64;

    const float* Xs[4] = { x,  img, txt, aud };
    const float* Ws[4] = { Wg, Wi,  Wt,  Wa  };

    // staging role: row sr (and sr+32), float4-col sc -> 8 rows x 128 B
    // contiguous per wave-instr (16 lines, same as rounds 2-3).
    const int sc = t & 7;
    const int sr = t >> 3;   // 0..31

    // ---- prologue: stage pass 0 (modality 0, s=0) ----
    {
        const float* src = Xs[0] + (size_t)tok0 * kH + hbase + sc * 4;
        const float4 va = *(const float4*)(src + (size_t)sr * kH);
        const float4 vb = *(const float4*)(src + (size_t)(sr + 32) * kH);
        *(float4*)&smem[sr * 36 + sc * 4] = va;
        *(float4*)&smem[(sr + 32) * 36 + sc * 4] = vb;
    }
    __syncthreads();

    double dacc[kE];
#pragma unroll
    for (int e = 0; e < kE; ++e) dacc[e] = 0.0;
    float facc[kE];

#pragma unroll
    for (int p = 0; p < 8; ++p) {        // pass = (modality m = p>>1, half s = p&1)
        const int m = p >> 1;
        const int s = p & 1;

        // prefetch next pass's tile into registers (in flight during compute)
        float4 na, nb;
        if (p < 7) {
            const int m2 = (p + 1) >> 1, s2 = (p + 1) & 1;
            const float* src = Xs[m2] + (size_t)tok0 * kH + hbase + s2 * 32 + sc * 4;
            na = *(const float4*)(src + (size_t)sr * kH);
            nb = *(const float4*)(src + (size_t)(sr + 32) * kH);
        }

        if (s == 0) {
#pragma unroll
            for (int e = 0; e < kE; ++e) facc[e] = 0.f;
        }

        const float* buf   = smem + (p & 1) * 2304;
        const float* wbase = Ws[m] + (size_t)(hbase + s * 32 + w * 8) * kE; // wave-uniform

#pragma unroll
        for (int k4 = 0; k4 < 2; ++k4) {
            const float4 xv = *(const float4*)&buf[ln * 36 + w * 8 + k4 * 4];
#pragma unroll
            for (int j = 0; j < 4; ++j) {
                const float xh = (j == 0) ? xv.x : (j == 1) ? xv.y : (j == 2) ? xv.z : xv.w;
                const float* wr = wbase + (k4 * 4 + j) * kE;   // wave-uniform -> s_load
                const float4 w0 = *(const float4*)(wr + 0);
                const float4 w1 = *(const float4*)(wr + 4);
                const float4 w2 = *(const float4*)(wr + 8);
                const float4 w3 = *(const float4*)(wr + 12);
                facc[0]  += xh * w0.x;  facc[1]  += xh * w0.y;
                facc[2]  += xh * w0.z;  facc[3]  += xh * w0.w;
                facc[4]  += xh * w1.x;  facc[5]  += xh * w1.y;
                facc[6]  += xh * w1.z;  facc[7]  += xh * w1.w;
                facc[8]  += xh * w2.x;  facc[9]  += xh * w2.y;
                facc[10] += xh * w2.z;  facc[11] += xh * w2.w;
                facc[12] += xh * w3.x;  facc[13] += xh * w3.y;
                facc[14] += xh * w3.z;  facc[15] += xh * w3.w;
            }
        }

        if (s == 1) {   // fold 16-h fp32 chunk into fp64
#pragma unroll
            for (int e = 0; e < kE; ++e) dacc[e] += (double)facc[e];
        }

        // write prefetched tile into the other buffer; barrier ends the pass
        if (p < 7) {
            float* nbuf = smem + ((p + 1) & 1) * 2304;
            *(float4*)&nbuf[sr * 36 + sc * 4] = na;
            *(float4*)&nbuf[(sr + 32) * 36 + sc * 4] = nb;
        }
        __syncthreads();
    }

    // ---- cross-wave reduce: red[w][tok][e] (stride 20 floats, 16B-aligned) ----
#pragma unroll
    for (int q = 0; q < 4; ++q) {
        *(float4*)&smem[(w * 64 + ln) * 20 + q * 4] =
            make_float4((float)dacc[q * 4 + 0], (float)dacc[q * 4 + 1],
                        (float)dacc[q * 4 + 2], (float)dacc[q * 4 + 3]);
    }
    __syncthreads();
    {
        const int tok = t >> 2;
        const int eq  = t & 3;
        double s0 = 0.0, s1 = 0.0, s2 = 0.0, s3 = 0.0;
#pragma unroll
        for (int ww = 0; ww < 4; ++ww) {
            const float4 v = *(const float4*)&smem[(ww * 64 + tok) * 20 + eq * 4];
            s0 += (double)v.x;  s1 += (double)v.y;
            s2 += (double)v.z;  s3 += (double)v.w;
        }
        // coalesced float4 store of the fp32 partial [hs][tok][e]
        *(float4*)&partials[((size_t)hs * kTokens + tok0 + tok) * kE + eq * 4] =
            make_float4((float)s0, (float)s1, (float)s2, (float)s3);
    }
}

// ---------------------------------------------------------------------------
// Stage 2: combine 16 chunk-partials + biases (fp64), softmax, top-k, output
// writes, per-block expert sums. Block = 64 tokens x 256 threads.
// ---------------------------------------------------------------------------
__global__ __launch_bounds__(256)
void router_topk(const float* __restrict__ partials,
                 const float* __restrict__ bg, const float* __restrict__ bi,
                 const float* __restrict__ bt, const float* __restrict__ ba,
                 float* __restrict__ out, float* __restrict__ blocksum)
{
    __shared__ double lgs[64][kE + 1];
    __shared__ float  pr[64][kE + 1];

    const int t    = threadIdx.x;
    const int tq   = t >> 2;      // token offset 0..63
    const int eq   = t & 3;       // e-quad
    const int tok0 = blockIdx.x * 64;

    double a0 = (double)bg[eq*4+0] + (double)bi[eq*4+0] + (double)bt[eq*4+0] + (double)ba[eq*4+0];
    double a1 = (double)bg[eq*4+1] + (double)bi[eq*4+1] + (double)bt[eq*4+1] + (double)ba[eq*4+1];
    double a2 = (double)bg[eq*4+2] + (double)bi[eq*4+2] + (double)bt[eq*4+2] + (double)ba[eq*4+2];
    double a3 = (double)bg[eq*4+3] + (double)bi[eq*4+3] + (double)bt[eq*4+3] + (double)ba[eq*4+3];

#pragma unroll
    for (int c = 0; c < kNC; ++c) {
        const float4 v = *(const float4*)(partials + ((size_t)c * kTokens + tok0 + tq) * kE + eq * 4);
        a0 += (double)v.x;  a1 += (double)v.y;  a2 += (double)v.z;  a3 += (double)v.w;
    }
    lgs[tq][eq*4+0] = a0;  lgs[tq][eq*4+1] = a1;
    lgs[tq][eq*4+2] = a2;  lgs[tq][eq*4+3] = a3;
    __syncthreads();

    if (t < 64) {
        const int tok = tok0 + t;
        double lg[kE];
#pragma unroll
        for (int e = 0; e < kE; ++e) lg[e] = lgs[t][e];

        double mx = lg[0];
#pragma unroll
        for (int e = 1; e < kE; ++e) mx = fmax(mx, lg[e]);

        float p[kE];
        float sum = 0.f;
#pragma unroll
        for (int e = 0; e < kE; ++e) {
            p[e] = expf((float)(lg[e] - mx));
            sum += p[e];
        }
        const float inv = 1.f / sum;
#pragma unroll
        for (int e = 0; e < kE; ++e) { p[e] *= inv; pr[t][e] = p[e]; }

        // top-4, descending, ties -> smallest index (matches jax.lax.top_k)
        unsigned used = 0;
        float tp[kTopK];
        int   ti[kTopK];
        float s4 = 0.f;
#pragma unroll
        for (int k = 0; k < kTopK; ++k) {
            float best = -1.f;
            int   bidx = 0;
#pragma unroll
            for (int e = 0; e < kE; ++e) {
                if (!((used >> e) & 1u) && p[e] > best) { best = p[e]; bidx = e; }
            }
            used |= 1u << bidx;
            tp[k] = best;
            ti[k] = bidx;
            s4 += best;
        }
        const float rn = 1.f / s4;

        *(float4*)&out[(size_t)tok * kTopK] =
            make_float4((float)ti[0], (float)ti[1], (float)ti[2], (float)ti[3]);
        *(float4*)&out[(size_t)kTokens * kTopK + (size_t)tok * kTopK] =
            make_float4(tp[0] * rn, tp[1] * rn, tp[2] * rn, tp[3] * rn);
    }
    __syncthreads();

    if (t < kE) {
        float s = 0.f;
#pragma unroll
        for (int tk = 0; tk < 64; ++tk) s += pr[tk][t];
        blocksum[blockIdx.x * kE + t] = s;
    }
}

// ---------------------------------------------------------------------------
// Stage 3: 128 block-partials -> mean prob per expert -> aux loss scalar
// ---------------------------------------------------------------------------
__global__ __launch_bounds__(64)
void router_aux(const float* __restrict__ blocksum, float* __restrict__ out)
{
    __shared__ double ps[kE];
    const int t = threadIdx.x;
    if (t < kE) {
        double s = 0.0;
        for (int b = 0; b < 128; ++b) s += (double)blocksum[b * kE + t];
        ps[t] = s / (double)kTokens;
    }
    __syncthreads();
    if (t == 0) {
        double aux = 0.0;
#pragma unroll
        for (int e = 0; e < kE; ++e) aux += ps[e] * log(ps[e] * (double)kE + 1e-9);
        out[(size_t)kTokens * kTopK * 2] = (float)aux;  // element 65536
    }
}

extern "C" void kernel_launch(void* const* d_in, const int* in_sizes, int n_in,
                              void* d_out, int out_size, void* d_ws, size_t ws_size,
                              hipStream_t stream)
{
    const float* x   = (const float*)d_in[0];
    const float* img = (const float*)d_in[1];
    const float* txt = (const float*)d_in[2];
    const float* aud = (const float*)d_in[3];
    const float* Wg  = (const float*)d_in[4];
    const float* bg  = (const float*)d_in[5];
    const float* Wi  = (const float*)d_in[6];
    const float* bi  = (const float*)d_in[7];
    const float* Wt  = (const float*)d_in[8];
    const float* bt  = (const float*)d_in[9];
    const float* Wa  = (const float*)d_in[10];
    const float* ba  = (const float*)d_in[11];

    float* out      = (float*)d_out;
    float* partials = (float*)d_ws;   // 16*8192*16*4 = 8 MB (ws >= 8.4 MB proven round 3)
    float* blocksum = (float*)((char*)d_ws + (size_t)kNC * kTokens * kE * 4);  // 8 KB

    router_fmac<<<2048, 256, 0, stream>>>(x, img, txt, aud, Wg, Wi, Wt, Wa, partials);
    router_topk<<<128, 256, 0, stream>>>(partials, bg, bi, bt, ba, out, blocksum);
    router_aux<<<1, 64, 0, stream>>>(blocksum, out);
}